// Round 1
// baseline (1148.672 us; speedup 1.0000x reference)
//
#include <hip/hip_runtime.h>

// ---------------------------------------------------------------------------
// MultiScaleRetention forward, MI355X/gfx950.  B=1,T=4096,E=1024,VD=2048,H=8.
// R3: k_attn latency attack — K-fragment register double-buffer (one tile
// ahead), V loads issued at tile top (hide under QK chain), s-chunk split of
// long blocks (tiles>40) with fp32 atomic O/den accumulation, normalization
// folded into k_rmsgate. setprio(1) around MFMA clusters.
// ---------------------------------------------------------------------------

typedef __attribute__((ext_vector_type(8)))  short  short8;
typedef __attribute__((ext_vector_type(16))) float  floatx16;

__device__ inline unsigned short f2bf(float f){
  unsigned int u = __builtin_bit_cast(unsigned int, f);
  unsigned int r = (u + 0x7fffu + ((u >> 16) & 1u)) >> 16;   // RNE
  return (unsigned short)r;
}
__device__ inline float bf2f(unsigned short u){
  unsigned int x = ((unsigned int)u) << 16;
  return __builtin_bit_cast(float, x);
}
__device__ inline void async_cp16(const void* g, const void* l){
  __builtin_amdgcn_global_load_lds((const __attribute__((address_space(1))) void*)g,
                                   (__attribute__((address_space(3))) void*)l, 16, 0, 0);
}

// ---------------- x -> bf16 -------------------------------------------------
struct us4 { unsigned short a,b,c,d; };
__global__ void k_cvt_x(const float* __restrict__ x, unsigned short* __restrict__ xb, int n4){
  int i = blockIdx.x*blockDim.x + threadIdx.x;
  if (i >= n4) return;
  float4 v = ((const float4*)x)[i];
  us4 o = { f2bf(v.x), f2bf(v.y), f2bf(v.z), f2bf(v.w) };
  ((us4*)xb)[i] = o;
}

// ---------------- fused weight transposes (fp32 RxC -> bf16 CxR) ------------
struct WPrep  { const float* src; unsigned short* dst; int R; int C; int ntile; };
struct WPrepAll { WPrep w[5]; };
__global__ __launch_bounds__(256) void k_prep_w(WPrepAll a){
  __shared__ float tile[64][65];
  int b = blockIdx.x, i = 0;
  while (b >= a.w[i].ntile){ b -= a.w[i].ntile; ++i; }
  const float* src = a.w[i].src; unsigned short* dst = a.w[i].dst;
  int R = a.w[i].R, C = a.w[i].C;
  int tpr = C >> 6;
  int c0 = (b % tpr)*64, r0 = (b / tpr)*64;
  #pragma unroll
  for (int j=0;j<16;++j){
    int idx = j*256 + threadIdx.x; int r = idx>>6, c = idx&63;
    tile[r][c] = src[(size_t)(r0+r)*C + c0 + c];
  }
  __syncthreads();
  #pragma unroll
  for (int j=0;j<16;++j){
    int idx = j*256 + threadIdx.x; int r = idx>>6, c = idx&63;
    dst[(size_t)(c0+r)*R + r0 + c] = f2bf(tile[c][r]);
  }
}

// ---------------- bf16 (R,C) -> bf16 (C,R) transpose ------------------------
__global__ __launch_bounds__(256) void k_transpose_b2b(const unsigned short* __restrict__ src,
    unsigned short* __restrict__ dst, int R, int C){
  __shared__ unsigned short tile[64][72];
  int c0 = blockIdx.x*64, r0 = blockIdx.y*64;
  #pragma unroll
  for (int i=0;i<16;++i){
    int idx = i*256 + threadIdx.x; int r = idx>>6, c = idx&63;
    tile[r][c] = src[(size_t)(r0+r)*C + c0 + c];
  }
  __syncthreads();
  #pragma unroll
  for (int i=0;i<16;++i){
    int idx = i*256 + threadIdx.x; int r = idx>>6, c = idx&63;
    dst[(size_t)(c0+r)*R + r0 + c] = tile[c][r];
  }
}

// ---------------- bf16 GEMM: C(M,N) = A(M,K) * BT(N,K)^T --------------------
template<int MODE>
__global__ __launch_bounds__(256) void k_gemm_bt(
    const unsigned short* __restrict__ A, const unsigned short* __restrict__ BT,
    int M, int N, int K,
    float* __restrict__ out_f32, unsigned short* __restrict__ out_v,
    unsigned short* __restrict__ out_g)
{
  __shared__ __align__(16) short As[128*64];
  __shared__ __align__(16) short Bs[128*64];
  int bn = blockIdx.x*128, bm = blockIdx.y*128;
  int tid = threadIdx.x;
  int w = tid>>6, l = tid&63;
  int wr = w>>1, wc = w&1;
  int lrow = l&31, lhi = l>>5;
  floatx16 acc[2][2];
  #pragma unroll
  for (int a=0;a<2;++a)
    #pragma unroll
    for (int b=0;b<2;++b)
      #pragma unroll
      for (int j=0;j<16;++j) acc[a][b][j]=0.f;

  int kchunk = K / gridDim.z;
  int k_beg = blockIdx.z * kchunk;
  for (int k0=k_beg; k0<k_beg+kchunk; k0+=64){
    __syncthreads();
    #pragma unroll
    for (int i=0;i<4;++i){
      int idx = i*256 + tid; int r = idx>>3, c = idx&7;
      int cs = c ^ (r&7);
      async_cp16((const char*)A  + ((size_t)(bm+r)*K + k0 + cs*8)*2, &As[idx*8]);
      async_cp16((const char*)BT + ((size_t)(bn+r)*K + k0 + cs*8)*2, &Bs[idx*8]);
    }
    __syncthreads();
    #pragma unroll
    for (int kc=0;kc<4;++kc){
      short8 af[2], bf[2];
      #pragma unroll
      for (int tm=0;tm<2;++tm){
        int row = wr*64 + tm*32 + lrow;
        int pos = (2*kc + lhi) ^ (row&7);
        af[tm] = *(const short8*)&As[row*64 + pos*8];
      }
      #pragma unroll
      for (int tn=0;tn<2;++tn){
        int row = wc*64 + tn*32 + lrow;
        int pos = (2*kc + lhi) ^ (row&7);
        bf[tn] = *(const short8*)&Bs[row*64 + pos*8];
      }
      #pragma unroll
      for (int tm=0;tm<2;++tm)
        #pragma unroll
        for (int tn=0;tn<2;++tn)
          acc[tm][tn] = __builtin_amdgcn_mfma_f32_32x32x16_bf16(af[tm], bf[tn], acc[tm][tn], 0,0,0);
    }
  }
  #pragma unroll
  for (int tm=0;tm<2;++tm)
    #pragma unroll
    for (int tn=0;tn<2;++tn)
      #pragma unroll
      for (int r=0;r<16;++r){
        int row = bm + wr*64 + tm*32 + (r&3) + 8*(r>>2) + 4*lhi;
        int col = bn + wc*64 + tn*32 + lrow;
        float v = acc[tm][tn][r];
        if (MODE==0){
          if (col < 2048)      out_f32[(size_t)row*2048 + col] = v;
          else if (col < 4096) out_v[(size_t)row*2048 + (col-2048)] = f2bf(v);
          else                 out_g[(size_t)row*2048 + (col-4096)] = f2bf(v);
        } else {
          atomicAdd(&out_f32[(size_t)row*N + col], v);
        }
      }
}

// ---------------- rotary (theta shift) + k scaling, fp32 -> bf16 ------------
__global__ void k_rotary(const float* __restrict__ qk, const float* __restrict__ sinp,
                         const float* __restrict__ cosp,
                         unsigned short* __restrict__ qrp, unsigned short* __restrict__ krp)
{
  int tid = blockIdx.x*blockDim.x + threadIdx.x;   // T*1024 pair-units
  int t = tid >> 10, p = tid & 1023;
  bool isq = p < 512;
  int c = (isq ? p : p - 512)*2;
  int d = c & 127;
  const float* base = qk + (size_t)t*2048 + (isq ? 0 : 1024) + c;
  float f0 = base[0], f1 = base[1];
  float s0 = sinp[t*128 + d],   s1 = sinp[t*128 + d + 1];
  float c0 = cosp[t*128 + d],   c1 = cosp[t*128 + d + 1];
  float r0 = f0*c0 - f1*s0;
  float r1 = f1*c1 + f0*s1;
  if (!isq){ r0 *= 0.08838834764831845f; r1 *= 0.08838834764831845f; }  // KD^-0.5
  unsigned short* dst = (isq ? qrp : krp) + (size_t)t*1024 + c;
  dst[0] = f2bf(r0); dst[1] = f2bf(r1);
}

// ---------------- retention attention (barrier-free, pipelined) -------------
// 1024 blocks: gid&7 = head (keeps head<->XCD affinity for L2 residency),
// gid>>3 = [qt descending]x[chunk]. 4 waves/block = (qhalf x hdhalf); each
// wave 32 q-rows x 128 hd. Long blocks (>40 s-tiles) split into 2 s-chunks;
// partial O / den accumulated with fp32 atomics into zeroed buffers, final
// clip+divide happens in k_rmsgate. Inner loop: K fragments double-buffered
// one tile ahead in registers, V loads issued at tile top (latency hidden
// under QK MFMA chain + P phase). No barriers anywhere.
__global__ __launch_bounds__(256, 2) void k_attn(
    const unsigned short* __restrict__ qr, const unsigned short* __restrict__ kr,
    const unsigned short* __restrict__ vT, float* __restrict__ o_acc,
    float* __restrict__ den_g)
{
  __shared__ __align__(16) short Ps[4][32*40];   // per-wave 32 rows x 40 shorts
  int gid = blockIdx.x;
  int head = gid & 7;
  int rest = gid >> 3;                           // 0..127
  int qt = 63 - (rest >> 1);                     // longest blocks first
  int chunk = rest & 1;
  int tid = threadIdx.x;
  int w = tid>>6, l = tid&63;
  int qh = w>>1, hh = w&1;
  int lrow = l&31, lhi = l>>5;
  int tbase = qt*64 + qh*32;                     // wave's first q-row

  float gamma = 1.f - exp2f(-5.f - (float)head);
  float L = log2f(gamma);                        // negative

  int dmax = (int)(40.0f/(-L));                  // decay < 2^-40 beyond: skip
  int s_start = tbase - dmax; if (s_start < 0) s_start = 0; s_start &= ~31;
  int N = ((tbase - s_start) >> 5) + 1;          // number of 32-col s-tiles
  bool split = (N > 40);
  int t0, t1;
  if (split){ int half = (N+1)>>1; t0 = chunk ? half : 0; t1 = chunk ? N : half; }
  else      { t0 = 0;              t1 = chunk ? 0 : N; }
  if (t0 >= t1) return;                          // wave-uniform exit, no barriers
  int sb = s_start + t0*32;
  int se = s_start + (t1-1)*32;                  // last tile start

  short8 qf[8];
  const unsigned short* qbase = qr + (size_t)(tbase+lrow)*1024 + head*128 + lhi*8;
  #pragma unroll
  for (int kc=0;kc<8;++kc) qf[kc] = *(const short8*)(qbase + kc*16);

  floatx16 o[4];
  #pragma unroll
  for (int i=0;i<4;++i)
    #pragma unroll
    for (int j=0;j<16;++j) o[i][j]=0.f;
  float den[16];
  #pragma unroll
  for (int r=0;r<16;++r) den[r]=0.f;
  float rowf[16];
  #pragma unroll
  for (int r=0;r<16;++r){
    int row = (r&3)+8*(r>>2)+4*lhi;
    rowf[r] = exp2f(L*(float)row);
  }
  float colf = exp2f(-L*(float)lrow);

  short* myP = &Ps[w][0];
  const unsigned short* kb = kr + head*128 + lhi*8;
  const unsigned short* vb = vT + (size_t)(head*256 + hh*128)*4096 + lhi*8;

#define LOADK(S0, KF) do{ \
    const unsigned short* kp_ = kb + (size_t)((S0)+lrow)*1024; \
    _Pragma("unroll") \
    for (int kc=0;kc<8;++kc) KF[kc] = *(const short8*)(kp_ + kc*16); \
  }while(0)

#define LOADV(S0, VF) do{ \
    const unsigned short* vp_ = vb + (S0); \
    _Pragma("unroll") \
    for (int nt=0;nt<4;++nt){ \
      const unsigned short* vr_ = vp_ + (size_t)(nt*32+lrow)*4096; \
      _Pragma("unroll") \
      for (int kc=0;kc<2;++kc) VF[nt*2+kc] = *(const short8*)(vr_ + kc*16); \
    } \
  }while(0)

#define COMPUTE(S0, KF, VF) do{ \
    floatx16 s_; \
    _Pragma("unroll") for (int j=0;j<16;++j) s_[j]=0.f; \
    __builtin_amdgcn_s_setprio(1); \
    _Pragma("unroll") \
    for (int kc=0;kc<8;++kc) \
      s_ = __builtin_amdgcn_mfma_f32_32x32x16_bf16(qf[kc], KF[kc], s_, 0,0,0); \
    __builtin_amdgcn_s_setprio(0); \
    float tf_ = exp2f(L*(float)(tbase - (S0))); \
    float tcf_ = tf_*colf; \
    bool diag_ = ((S0) + 31 > tbase); \
    _Pragma("unroll") \
    for (int r=0;r<16;++r){ \
      int row_ = (r&3)+8*(r>>2)+4*lhi; \
      float val_ = s_[r]*(tcf_*rowf[r]); \
      if (diag_){ if (tbase+row_ < (S0)+lrow) val_ = 0.f; } \
      den[r] += fabsf(val_); \
      myP[row_*40 + lrow] = (short)f2bf(val_); \
    } \
    short8 pa_[2]; \
    _Pragma("unroll") \
    for (int kc=0;kc<2;++kc) pa_[kc] = *(const short8*)&myP[lrow*40 + kc*16 + lhi*8]; \
    __builtin_amdgcn_s_setprio(1); \
    _Pragma("unroll") \
    for (int nt=0;nt<4;++nt){ \
      _Pragma("unroll") \
      for (int kc=0;kc<2;++kc) \
        o[nt] = __builtin_amdgcn_mfma_f32_32x32x16_bf16(pa_[kc], VF[nt*2+kc], o[nt], 0,0,0); \
    } \
    __builtin_amdgcn_s_setprio(0); \
  }while(0)

  short8 kfA[8], kfB[8];
  LOADK(sb, kfA);
  for (int s0 = sb;; s0 += 64){
    {
      short8 vfA[8];
      LOADV(s0, vfA);                            // V latency hides under QK+P
      if (s0 + 32 <= se) LOADK(s0+32, kfB);      // K one tile ahead
      COMPUTE(s0, kfA, vfA);
    }
    if (s0 + 32 > se) break;
    {
      short8 vfB[8];
      LOADV(s0+32, vfB);
      if (s0 + 64 <= se) LOADK(s0+64, kfA);
      COMPUTE(s0+32, kfB, vfB);
    }
    if (s0 + 64 > se) break;
  }
#undef LOADK
#undef LOADV
#undef COMPUTE

  // den: reduce across the 32 cols of this wave's tile set, then atomic-add
  // per q-row. Only hh==0 waves contribute (hh waves compute identical P).
  if (hh == 0){
    #pragma unroll
    for (int r=0;r<16;++r){
      float d = den[r];
      #pragma unroll
      for (int off=1; off<32; off<<=1) d += __shfl_xor(d, off, 64);
      if (lrow == 0){
        int row = (r&3)+8*(r>>2)+4*lhi;
        atomicAdd(&den_g[(size_t)(tbase+row)*8 + head], d);
      }
    }
  }

  // O: plain store when this wave owns its rows alone, atomic when s-split.
  #pragma unroll
  for (int nt=0;nt<4;++nt)
    #pragma unroll
    for (int r=0;r<16;++r){
      int row = (r&3)+8*(r>>2)+4*lhi;
      float* dst = &o_acc[(size_t)(tbase+row)*2048 + head*256 + hh*128 + nt*32 + lrow];
      float v = o[nt][r];
      if (split) atomicAdd(dst, v);
      else       *dst = v;
    }
}

// ---------------- den-normalize + group RMS + SiLU gate ---------------------
__global__ __launch_bounds__(256) void k_rmsgate(const float* __restrict__ o_acc,
    const unsigned short* __restrict__ g_bf, const float* __restrict__ den_g,
    unsigned short* __restrict__ gated)
{
  int t = blockIdx.x;
  int tid = threadIdx.x;
  int head = tid >> 5;                       // 32 threads = one head group (256)
  float den = den_g[(size_t)t*8 + head];
  float rs  = 1.0f/fminf(fmaxf(den, 1.0f), 50000.0f);
  size_t base = (size_t)t*2048 + tid*8;
  float4 o0 = *(const float4*)(o_acc + base);
  float4 o1 = *(const float4*)(o_acc + base + 4);
  short8 gv = *(const short8*)(g_bf + base);
  float of[8] = {o0.x,o0.y,o0.z,o0.w,o1.x,o1.y,o1.z,o1.w};
  float ss = 0.f;
  #pragma unroll
  for (int j=0;j<8;++j){
    of[j] *= rs;
    ss += of[j]*of[j];
  }
  #pragma unroll
  for (int off=1; off<32; off<<=1) ss += __shfl_xor(ss, off, 64);
  float rms = rsqrtf(ss*(1.0f/256.0f) + 1e-6f);
  short8 outv;
  #pragma unroll
  for (int j=0;j<8;++j){
    float g = bf2f((unsigned short)gv[j]);
    float si = g / (1.0f + expf(-g));
    outv[j] = (short)f2bf(si * of[j] * rms);
  }
  *(short8*)(gated + base) = outv;
}

// ---------------------------------------------------------------------------
extern "C" void kernel_launch(void* const* d_in, const int* in_sizes, int n_in,
                              void* d_out, int out_size, void* d_ws, size_t ws_size,
                              hipStream_t stream)
{
  const float* x    = (const float*)d_in[0];
  const float* sinp = (const float*)d_in[1];
  const float* cosp = (const float*)d_in[2];
  // d_in[3] = inner_mask: intentionally unused (computed analytically)
  const float* Wq = (const float*)d_in[4];
  const float* Wk = (const float*)d_in[5];
  const float* Wv = (const float*)d_in[6];
  const float* Wg = (const float*)d_in[7];
  const float* Wo = (const float*)d_in[8];

  char* ws = (char*)d_ws;
  size_t off = 0;
  auto alloc = [&](size_t bytes)->char*{ char* p = ws + off; off += (bytes + 255) & ~(size_t)255; return p; };
  unsigned short* x_bf   = (unsigned short*)alloc((size_t)4096*1024*2);  // reused as qr, then gated
  unsigned short* WallT  = (unsigned short*)alloc((size_t)6144*1024*2);  // reused as kr
  float*          qk_f32 = (float*)         alloc((size_t)4096*2048*4);  // reused as o_acc (fp32)
  unsigned short* v_bf   = (unsigned short*)alloc((size_t)4096*2048*2);
  unsigned short* g_bf   = (unsigned short*)alloc((size_t)4096*2048*2);
  unsigned short* vT     = (unsigned short*)alloc((size_t)2048*4096*2);
  unsigned short* WoT    = (unsigned short*)alloc((size_t)1024*2048*2);
  float*          den_g  = (float*)         alloc((size_t)4096*8*4);
  unsigned short* qrp    = x_bf;                    // alias (x_bf dead after qkvg GEMM)
  unsigned short* krp    = WallT;                   // alias (WallT dead after qkvg GEMM)
  float*          o_acc  = qk_f32;                  // alias (qk_f32 dead after rotary)
  unsigned short* gated  = x_bf;                    // alias (qr/kr dead after k_attn; spans x_bf+WallT)

  // d_out is poisoned 0xAA; final GEMM uses atomic split-K -> zero it early
  hipMemsetAsync(d_out, 0, (size_t)4096*1024*4, stream);

  // prep
  k_cvt_x<<<4096, 256, 0, stream>>>(x, x_bf, 4096*1024/4);
  WPrepAll pa;
  pa.w[0] = { Wq, WallT,                        1024, 1024, 256 };
  pa.w[1] = { Wk, WallT + 1024*1024,            1024, 1024, 256 };
  pa.w[2] = { Wv, WallT + 2048*1024,            1024, 2048, 512 };
  pa.w[3] = { Wg, WallT + (size_t)4096*1024,    1024, 2048, 512 };
  pa.w[4] = { Wo, WoT,                          2048, 1024, 512 };
  k_prep_w<<<2048, 256, 0, stream>>>(pa);

  // qkvg = x @ [Wq|Wk|Wv|Wg]
  k_gemm_bt<0><<<dim3(48,32,1), 256, 0, stream>>>(x_bf, WallT, 4096, 6144, 1024, qk_f32, v_bf, g_bf);

  // rotary + k-scaling -> bf16 (overwrites x_bf/WallT aliases)
  k_rotary<<<16384, 256, 0, stream>>>(qk_f32, sinp, cosp, qrp, krp);

  // V^T per head: (t, 2048) -> (2048, t)
  k_transpose_b2b<<<dim3(32,64), 256, 0, stream>>>(v_bf, vT, 4096, 2048);

  // attention accumulators (qk_f32 is dead after rotary; atomics need zeros)
  hipMemsetAsync(o_acc, 0, (size_t)4096*2048*4, stream);
  hipMemsetAsync(den_g, 0, (size_t)4096*8*4, stream);

  // retention attention -> unnormalized o_acc (fp32) + den_g
  k_attn<<<1024, 256, 0, stream>>>(qrp, krp, vT, o_acc, den_g);

  // den-clip divide + RMS(group=256) + silu(g) gate -> gated bf16
  k_rmsgate<<<4096, 256, 0, stream>>>(o_acc, g_bf, den_g, gated);

  // out = gated @ Wo -> fp32 d_out (split-K=2, atomic accumulate)
  k_gemm_bt<1><<<dim3(8,32,2), 256, 0, stream>>>(gated, WoT, 4096, 1024, 2048,
                                                 (float*)d_out, nullptr, nullptr);

  (void)in_sizes; (void)n_in; (void)out_size; (void)ws_size;
}

// Round 2
// 1070.938 us; speedup vs baseline: 1.0726x; 1.0726x over previous
//
#include <hip/hip_runtime.h>

// ---------------------------------------------------------------------------
// MultiScaleRetention forward, MI355X/gfx950.  B=1,T=4096,E=1024,VD=2048,H=8.
// R4: k_attn — always-split every (head,qtile) block into 2 s-chunks with
// ATOMIC-FREE fp32 partial accumulation (chunk-private O/den buffers, summed
// in k_rmsgate). R3's atomics caused 326MB of HBM write traffic; partials are
// plain coalesced stores (~64MB). Keeps K-fragment register double-buffer,
// early V loads, setprio around MFMA clusters, longest-first ordering.
// ---------------------------------------------------------------------------

typedef __attribute__((ext_vector_type(8)))  short  short8;
typedef __attribute__((ext_vector_type(16))) float  floatx16;

__device__ inline unsigned short f2bf(float f){
  unsigned int u = __builtin_bit_cast(unsigned int, f);
  unsigned int r = (u + 0x7fffu + ((u >> 16) & 1u)) >> 16;   // RNE
  return (unsigned short)r;
}
__device__ inline float bf2f(unsigned short u){
  unsigned int x = ((unsigned int)u) << 16;
  return __builtin_bit_cast(float, x);
}
__device__ inline void async_cp16(const void* g, const void* l){
  __builtin_amdgcn_global_load_lds((const __attribute__((address_space(1))) void*)g,
                                   (__attribute__((address_space(3))) void*)l, 16, 0, 0);
}

// ---------------- x -> bf16 -------------------------------------------------
struct us4 { unsigned short a,b,c,d; };
__global__ void k_cvt_x(const float* __restrict__ x, unsigned short* __restrict__ xb, int n4){
  int i = blockIdx.x*blockDim.x + threadIdx.x;
  if (i >= n4) return;
  float4 v = ((const float4*)x)[i];
  us4 o = { f2bf(v.x), f2bf(v.y), f2bf(v.z), f2bf(v.w) };
  ((us4*)xb)[i] = o;
}

// ---------------- fused weight transposes (fp32 RxC -> bf16 CxR) ------------
struct WPrep  { const float* src; unsigned short* dst; int R; int C; int ntile; };
struct WPrepAll { WPrep w[5]; };
__global__ __launch_bounds__(256) void k_prep_w(WPrepAll a){
  __shared__ float tile[64][65];
  int b = blockIdx.x, i = 0;
  while (b >= a.w[i].ntile){ b -= a.w[i].ntile; ++i; }
  const float* src = a.w[i].src; unsigned short* dst = a.w[i].dst;
  int R = a.w[i].R, C = a.w[i].C;
  int tpr = C >> 6;
  int c0 = (b % tpr)*64, r0 = (b / tpr)*64;
  #pragma unroll
  for (int j=0;j<16;++j){
    int idx = j*256 + threadIdx.x; int r = idx>>6, c = idx&63;
    tile[r][c] = src[(size_t)(r0+r)*C + c0 + c];
  }
  __syncthreads();
  #pragma unroll
  for (int j=0;j<16;++j){
    int idx = j*256 + threadIdx.x; int r = idx>>6, c = idx&63;
    dst[(size_t)(c0+r)*R + r0 + c] = f2bf(tile[c][r]);
  }
}

// ---------------- bf16 (R,C) -> bf16 (C,R) transpose ------------------------
__global__ __launch_bounds__(256) void k_transpose_b2b(const unsigned short* __restrict__ src,
    unsigned short* __restrict__ dst, int R, int C){
  __shared__ unsigned short tile[64][72];
  int c0 = blockIdx.x*64, r0 = blockIdx.y*64;
  #pragma unroll
  for (int i=0;i<16;++i){
    int idx = i*256 + threadIdx.x; int r = idx>>6, c = idx&63;
    tile[r][c] = src[(size_t)(r0+r)*C + c0 + c];
  }
  __syncthreads();
  #pragma unroll
  for (int i=0;i<16;++i){
    int idx = i*256 + threadIdx.x; int r = idx>>6, c = idx&63;
    dst[(size_t)(c0+r)*R + r0 + c] = tile[c][r];
  }
}

// ---------------- bf16 GEMM: C(M,N) = A(M,K) * BT(N,K)^T --------------------
template<int MODE>
__global__ __launch_bounds__(256) void k_gemm_bt(
    const unsigned short* __restrict__ A, const unsigned short* __restrict__ BT,
    int M, int N, int K,
    float* __restrict__ out_f32, unsigned short* __restrict__ out_v,
    unsigned short* __restrict__ out_g)
{
  __shared__ __align__(16) short As[128*64];
  __shared__ __align__(16) short Bs[128*64];
  int bn = blockIdx.x*128, bm = blockIdx.y*128;
  int tid = threadIdx.x;
  int w = tid>>6, l = tid&63;
  int wr = w>>1, wc = w&1;
  int lrow = l&31, lhi = l>>5;
  floatx16 acc[2][2];
  #pragma unroll
  for (int a=0;a<2;++a)
    #pragma unroll
    for (int b=0;b<2;++b)
      #pragma unroll
      for (int j=0;j<16;++j) acc[a][b][j]=0.f;

  int kchunk = K / gridDim.z;
  int k_beg = blockIdx.z * kchunk;
  for (int k0=k_beg; k0<k_beg+kchunk; k0+=64){
    __syncthreads();
    #pragma unroll
    for (int i=0;i<4;++i){
      int idx = i*256 + tid; int r = idx>>3, c = idx&7;
      int cs = c ^ (r&7);
      async_cp16((const char*)A  + ((size_t)(bm+r)*K + k0 + cs*8)*2, &As[idx*8]);
      async_cp16((const char*)BT + ((size_t)(bn+r)*K + k0 + cs*8)*2, &Bs[idx*8]);
    }
    __syncthreads();
    #pragma unroll
    for (int kc=0;kc<4;++kc){
      short8 af[2], bf[2];
      #pragma unroll
      for (int tm=0;tm<2;++tm){
        int row = wr*64 + tm*32 + lrow;
        int pos = (2*kc + lhi) ^ (row&7);
        af[tm] = *(const short8*)&As[row*64 + pos*8];
      }
      #pragma unroll
      for (int tn=0;tn<2;++tn){
        int row = wc*64 + tn*32 + lrow;
        int pos = (2*kc + lhi) ^ (row&7);
        bf[tn] = *(const short8*)&Bs[row*64 + pos*8];
      }
      #pragma unroll
      for (int tm=0;tm<2;++tm)
        #pragma unroll
        for (int tn=0;tn<2;++tn)
          acc[tm][tn] = __builtin_amdgcn_mfma_f32_32x32x16_bf16(af[tm], bf[tn], acc[tm][tn], 0,0,0);
    }
  }
  #pragma unroll
  for (int tm=0;tm<2;++tm)
    #pragma unroll
    for (int tn=0;tn<2;++tn)
      #pragma unroll
      for (int r=0;r<16;++r){
        int row = bm + wr*64 + tm*32 + (r&3) + 8*(r>>2) + 4*lhi;
        int col = bn + wc*64 + tn*32 + lrow;
        float v = acc[tm][tn][r];
        if (MODE==0){
          if (col < 2048)      out_f32[(size_t)row*2048 + col] = v;
          else if (col < 4096) out_v[(size_t)row*2048 + (col-2048)] = f2bf(v);
          else                 out_g[(size_t)row*2048 + (col-4096)] = f2bf(v);
        } else {
          atomicAdd(&out_f32[(size_t)row*N + col], v);
        }
      }
}

// ---------------- rotary (theta shift) + k scaling, fp32 -> bf16 ------------
__global__ void k_rotary(const float* __restrict__ qk, const float* __restrict__ sinp,
                         const float* __restrict__ cosp,
                         unsigned short* __restrict__ qrp, unsigned short* __restrict__ krp)
{
  int tid = blockIdx.x*blockDim.x + threadIdx.x;   // T*1024 pair-units
  int t = tid >> 10, p = tid & 1023;
  bool isq = p < 512;
  int c = (isq ? p : p - 512)*2;
  int d = c & 127;
  const float* base = qk + (size_t)t*2048 + (isq ? 0 : 1024) + c;
  float f0 = base[0], f1 = base[1];
  float s0 = sinp[t*128 + d],   s1 = sinp[t*128 + d + 1];
  float c0 = cosp[t*128 + d],   c1 = cosp[t*128 + d + 1];
  float r0 = f0*c0 - f1*s0;
  float r1 = f1*c1 + f0*s1;
  if (!isq){ r0 *= 0.08838834764831845f; r1 *= 0.08838834764831845f; }  // KD^-0.5
  unsigned short* dst = (isq ? qrp : krp) + (size_t)t*1024 + c;
  dst[0] = f2bf(r0); dst[1] = f2bf(r1);
}

// ---------------- retention attention (barrier-free, pipelined, split) ------
// 1024 blocks: gid&7 = head (head<->XCD affinity), gid>>3 = [qt desc]x[chunk].
// 4 waves/block = (qhalf x hdhalf); wave = 32 q-rows x 128 hd. EVERY block's
// s-tile range is split in half across the two chunk blocks; each chunk
// plain-stores its fp32 partial O to its chunk-private buffer (zeros when the
// chunk is empty) and its reduced partial den to a chunk-private slot.
// k_rmsgate sums the two partials — no atomics, no memsets.
// Inner loop: K fragments double-buffered one tile ahead in registers, V
// loads issued at tile top (latency hides under QK MFMA chain + P phase).
// No barriers anywhere.
__global__ __launch_bounds__(256, 2) void k_attn(
    const unsigned short* __restrict__ qr, const unsigned short* __restrict__ kr,
    const unsigned short* __restrict__ vT,
    float* __restrict__ o_acc0, float* __restrict__ o_acc1,
    float* __restrict__ den_g)
{
  __shared__ __align__(16) short Ps[4][32*40];   // per-wave 32 rows x 40 shorts
  int gid = blockIdx.x;
  int head = gid & 7;
  int rest = gid >> 3;                           // 0..127
  int qt = 63 - (rest >> 1);                     // longest blocks first
  int chunk = rest & 1;
  int tid = threadIdx.x;
  int w = tid>>6, l = tid&63;
  int qh = w>>1, hh = w&1;
  int lrow = l&31, lhi = l>>5;
  int tbase = qt*64 + qh*32;                     // wave's first q-row

  float gamma = 1.f - exp2f(-5.f - (float)head);
  float L = log2f(gamma);                        // negative

  int dmax = (int)(40.0f/(-L));                  // decay < 2^-40 beyond: skip
  int s_start = tbase - dmax; if (s_start < 0) s_start = 0; s_start &= ~31;
  int N = ((tbase - s_start) >> 5) + 1;          // number of 32-col s-tiles
  int half = (N+1)>>1;                           // chunk0 = [0,half), chunk1 = [half,N)
  int t0 = chunk ? half : 0;
  int t1 = chunk ? N    : half;

  floatx16 o[4];
  #pragma unroll
  for (int i=0;i<4;++i)
    #pragma unroll
    for (int j=0;j<16;++j) o[i][j]=0.f;
  float den[16];
  #pragma unroll
  for (int r=0;r<16;++r) den[r]=0.f;

  if (t0 < t1){
    int sb = s_start + t0*32;
    int se = s_start + (t1-1)*32;                // last tile start

    short8 qf[8];
    const unsigned short* qbase = qr + (size_t)(tbase+lrow)*1024 + head*128 + lhi*8;
    #pragma unroll
    for (int kc=0;kc<8;++kc) qf[kc] = *(const short8*)(qbase + kc*16);

    float rowf[16];
    #pragma unroll
    for (int r=0;r<16;++r){
      int row = (r&3)+8*(r>>2)+4*lhi;
      rowf[r] = exp2f(L*(float)row);
    }
    float colf = exp2f(-L*(float)lrow);

    short* myP = &Ps[w][0];
    const unsigned short* kb = kr + head*128 + lhi*8;
    const unsigned short* vb = vT + (size_t)(head*256 + hh*128)*4096 + lhi*8;

#define LOADK(S0, KF) do{ \
    const unsigned short* kp_ = kb + (size_t)((S0)+lrow)*1024; \
    _Pragma("unroll") \
    for (int kc=0;kc<8;++kc) KF[kc] = *(const short8*)(kp_ + kc*16); \
  }while(0)

#define LOADV(S0, VF) do{ \
    const unsigned short* vp_ = vb + (S0); \
    _Pragma("unroll") \
    for (int nt=0;nt<4;++nt){ \
      const unsigned short* vr_ = vp_ + (size_t)(nt*32+lrow)*4096; \
      _Pragma("unroll") \
      for (int kc=0;kc<2;++kc) VF[nt*2+kc] = *(const short8*)(vr_ + kc*16); \
    } \
  }while(0)

#define COMPUTE(S0, KF, VF) do{ \
    floatx16 s_; \
    _Pragma("unroll") for (int j=0;j<16;++j) s_[j]=0.f; \
    __builtin_amdgcn_s_setprio(1); \
    _Pragma("unroll") \
    for (int kc=0;kc<8;++kc) \
      s_ = __builtin_amdgcn_mfma_f32_32x32x16_bf16(qf[kc], KF[kc], s_, 0,0,0); \
    __builtin_amdgcn_s_setprio(0); \
    float tf_ = exp2f(L*(float)(tbase - (S0))); \
    float tcf_ = tf_*colf; \
    bool diag_ = ((S0) + 31 > tbase); \
    _Pragma("unroll") \
    for (int r=0;r<16;++r){ \
      int row_ = (r&3)+8*(r>>2)+4*lhi; \
      float val_ = s_[r]*(tcf_*rowf[r]); \
      if (diag_){ if (tbase+row_ < (S0)+lrow) val_ = 0.f; } \
      den[r] += fabsf(val_); \
      myP[row_*40 + lrow] = (short)f2bf(val_); \
    } \
    short8 pa_[2]; \
    _Pragma("unroll") \
    for (int kc=0;kc<2;++kc) pa_[kc] = *(const short8*)&myP[lrow*40 + kc*16 + lhi*8]; \
    __builtin_amdgcn_s_setprio(1); \
    _Pragma("unroll") \
    for (int nt=0;nt<4;++nt){ \
      _Pragma("unroll") \
      for (int kc=0;kc<2;++kc) \
        o[nt] = __builtin_amdgcn_mfma_f32_32x32x16_bf16(pa_[kc], VF[nt*2+kc], o[nt], 0,0,0); \
    } \
    __builtin_amdgcn_s_setprio(0); \
  }while(0)

    short8 kfA[8], kfB[8];
    LOADK(sb, kfA);
    for (int s0 = sb;; s0 += 64){
      {
        short8 vfA[8];
        LOADV(s0, vfA);                          // V latency hides under QK+P
        if (s0 + 32 <= se) LOADK(s0+32, kfB);    // K one tile ahead
        COMPUTE(s0, kfA, vfA);
      }
      if (s0 + 32 > se) break;
      {
        short8 vfB[8];
        LOADV(s0+32, vfB);
        if (s0 + 64 <= se) LOADK(s0+64, kfA);
        COMPUTE(s0+32, kfB, vfB);
      }
      if (s0 + 64 > se) break;
    }
#undef LOADK
#undef LOADV
#undef COMPUTE
  }

  // partial den: reduce across this wave's 32 cols, plain store per q-row.
  // hh waves compute identical P; only hh==0 stores. Unique writer per
  // (chunk,row,head) -> no atomics.
  if (hh == 0){
    #pragma unroll
    for (int r=0;r<16;++r){
      float d = den[r];
      #pragma unroll
      for (int off=1; off<32; off<<=1) d += __shfl_xor(d, off, 64);
      if (lrow == 0){
        int row = (r&3)+8*(r>>2)+4*lhi;
        den_g[((size_t)chunk*4096 + tbase+row)*8 + head] = d;
      }
    }
  }

  // partial O: plain fp32 store to the chunk-private buffer (zeros if empty).
  float* ob = chunk ? o_acc1 : o_acc0;
  #pragma unroll
  for (int nt=0;nt<4;++nt)
    #pragma unroll
    for (int r=0;r<16;++r){
      int row = (r&3)+8*(r>>2)+4*lhi;
      ob[(size_t)(tbase+row)*2048 + head*256 + hh*128 + nt*32 + lrow] = o[nt][r];
    }
}

// ---------------- partial-sum + den-normalize + group RMS + SiLU gate -------
__global__ __launch_bounds__(256) void k_rmsgate(const float* __restrict__ o_acc0,
    const float* __restrict__ o_acc1, const unsigned short* __restrict__ g_bf,
    const float* __restrict__ den_g, unsigned short* __restrict__ gated)
{
  int t = blockIdx.x;
  int tid = threadIdx.x;
  int head = tid >> 5;                       // 32 threads = one head group (256)
  float den = den_g[(size_t)t*8 + head] + den_g[(size_t)(4096 + t)*8 + head];
  float rs  = 1.0f/fminf(fmaxf(den, 1.0f), 50000.0f);
  size_t base = (size_t)t*2048 + tid*8;
  float4 a0 = *(const float4*)(o_acc0 + base);
  float4 a1 = *(const float4*)(o_acc0 + base + 4);
  float4 b0 = *(const float4*)(o_acc1 + base);
  float4 b1 = *(const float4*)(o_acc1 + base + 4);
  short8 gv = *(const short8*)(g_bf + base);
  float of[8] = {a0.x+b0.x, a0.y+b0.y, a0.z+b0.z, a0.w+b0.w,
                 a1.x+b1.x, a1.y+b1.y, a1.z+b1.z, a1.w+b1.w};
  float ss = 0.f;
  #pragma unroll
  for (int j=0;j<8;++j){
    of[j] *= rs;
    ss += of[j]*of[j];
  }
  #pragma unroll
  for (int off=1; off<32; off<<=1) ss += __shfl_xor(ss, off, 64);
  float rms = rsqrtf(ss*(1.0f/256.0f) + 1e-6f);
  short8 outv;
  #pragma unroll
  for (int j=0;j<8;++j){
    float g = bf2f((unsigned short)gv[j]);
    float si = g / (1.0f + expf(-g));
    outv[j] = (short)f2bf(si * of[j] * rms);
  }
  *(short8*)(gated + base) = outv;
}

// ---------------------------------------------------------------------------
extern "C" void kernel_launch(void* const* d_in, const int* in_sizes, int n_in,
                              void* d_out, int out_size, void* d_ws, size_t ws_size,
                              hipStream_t stream)
{
  const float* x    = (const float*)d_in[0];
  const float* sinp = (const float*)d_in[1];
  const float* cosp = (const float*)d_in[2];
  // d_in[3] = inner_mask: intentionally unused (computed analytically)
  const float* Wq = (const float*)d_in[4];
  const float* Wk = (const float*)d_in[5];
  const float* Wv = (const float*)d_in[6];
  const float* Wg = (const float*)d_in[7];
  const float* Wo = (const float*)d_in[8];

  char* ws = (char*)d_ws;
  size_t off = 0;
  auto alloc = [&](size_t bytes)->char*{ char* p = ws + off; off += (bytes + 255) & ~(size_t)255; return p; };
  unsigned short* x_bf   = (unsigned short*)alloc((size_t)4096*1024*2);  // reused as qr, then gated
  unsigned short* WallT  = (unsigned short*)alloc((size_t)6144*1024*2);  // reused as kr, then gated tail
  float*          qk_f32 = (float*)         alloc((size_t)4096*2048*4);  // reused as o_acc0 (fp32)
  unsigned short* v_bf   = (unsigned short*)alloc((size_t)4096*2048*2);
  unsigned short* g_bf   = (unsigned short*)alloc((size_t)4096*2048*2);
  unsigned short* vT     = (unsigned short*)alloc((size_t)2048*4096*2);
  unsigned short* WoT    = (unsigned short*)alloc((size_t)1024*2048*2);
  float*          o_acc1 = (float*)         alloc((size_t)4096*2048*4);
  float*          den_g  = (float*)         alloc((size_t)2*4096*8*4);
  unsigned short* qrp    = x_bf;                    // alias (x_bf dead after qkvg GEMM)
  unsigned short* krp    = WallT;                   // alias (WallT dead after qkvg GEMM)
  float*          o_acc0 = qk_f32;                  // alias (qk_f32 dead after rotary)
  unsigned short* gated  = x_bf;                    // alias (qr/kr dead after k_attn; spans x_bf+WallT)

  // d_out is poisoned 0xAA; final GEMM uses atomic split-K -> zero it early
  hipMemsetAsync(d_out, 0, (size_t)4096*1024*4, stream);

  // prep
  k_cvt_x<<<4096, 256, 0, stream>>>(x, x_bf, 4096*1024/4);
  WPrepAll pa;
  pa.w[0] = { Wq, WallT,                        1024, 1024, 256 };
  pa.w[1] = { Wk, WallT + 1024*1024,            1024, 1024, 256 };
  pa.w[2] = { Wv, WallT + 2048*1024,            1024, 2048, 512 };
  pa.w[3] = { Wg, WallT + (size_t)4096*1024,    1024, 2048, 512 };
  pa.w[4] = { Wo, WoT,                          2048, 1024, 512 };
  k_prep_w<<<2048, 256, 0, stream>>>(pa);

  // qkvg = x @ [Wq|Wk|Wv|Wg]
  k_gemm_bt<0><<<dim3(48,32,1), 256, 0, stream>>>(x_bf, WallT, 4096, 6144, 1024, qk_f32, v_bf, g_bf);

  // rotary + k-scaling -> bf16 (overwrites x_bf/WallT aliases)
  k_rotary<<<16384, 256, 0, stream>>>(qk_f32, sinp, cosp, qrp, krp);

  // V^T per head: (t, 2048) -> (2048, t)
  k_transpose_b2b<<<dim3(32,64), 256, 0, stream>>>(v_bf, vT, 4096, 2048);

  // retention attention -> chunk-private fp32 partial O + partial den
  k_attn<<<1024, 256, 0, stream>>>(qrp, krp, vT, o_acc0, o_acc1, den_g);

  // partial-sum + den-clip divide + RMS(group=256) + silu(g) gate -> gated
  k_rmsgate<<<4096, 256, 0, stream>>>(o_acc0, o_acc1, g_bf, den_g, gated);

  // out = gated @ Wo -> fp32 d_out (split-K=2, atomic accumulate)
  k_gemm_bt<1><<<dim3(8,32,2), 256, 0, stream>>>(gated, WoT, 4096, 1024, 2048,
                                                 (float*)d_out, nullptr, nullptr);

  (void)in_sizes; (void)n_in; (void)out_size; (void)ws_size;
}

// Round 3
// 990.276 us; speedup vs baseline: 1.1600x; 1.0815x over previous
//
#include <hip/hip_runtime.h>

// ---------------------------------------------------------------------------
// MultiScaleRetention forward, MI355X/gfx950.  B=1,T=4096,E=1024,VD=2048,H=8.
// R5: k_attn — swapped QK^T (mfma(K,Q) -> C[s][q]) + in-register P transform
// (8x v_cvt_pk_bf16_f32 + 4x v_permlane32_swap_b32) eliminates the LDS P
// roundtrip and the 16x5-shfl den reduction (den is now a per-lane scalar).
// Partial O stored as bf16 (R2-measured clean write path; fp32 stores showed
// 5.8x fabric write amplification). LDS = 0. K dbuf + early V loads kept;
// higher reg budget should let the prefetch actually stay hoisted.
// ---------------------------------------------------------------------------

typedef __attribute__((ext_vector_type(8)))  short  short8;
typedef __attribute__((ext_vector_type(16))) float  floatx16;

__device__ inline unsigned short f2bf(float f){
  unsigned int u = __builtin_bit_cast(unsigned int, f);
  unsigned int r = (u + 0x7fffu + ((u >> 16) & 1u)) >> 16;   // RNE
  return (unsigned short)r;
}
__device__ inline float bf2f(unsigned short u){
  unsigned int x = ((unsigned int)u) << 16;
  return __builtin_bit_cast(float, x);
}
__device__ inline void async_cp16(const void* g, const void* l){
  __builtin_amdgcn_global_load_lds((const __attribute__((address_space(1))) void*)g,
                                   (__attribute__((address_space(3))) void*)l, 16, 0, 0);
}

// ---------------- x -> bf16 -------------------------------------------------
struct us4 { unsigned short a,b,c,d; };
__global__ void k_cvt_x(const float* __restrict__ x, unsigned short* __restrict__ xb, int n4){
  int i = blockIdx.x*blockDim.x + threadIdx.x;
  if (i >= n4) return;
  float4 v = ((const float4*)x)[i];
  us4 o = { f2bf(v.x), f2bf(v.y), f2bf(v.z), f2bf(v.w) };
  ((us4*)xb)[i] = o;
}

// ---------------- fused weight transposes (fp32 RxC -> bf16 CxR) ------------
struct WPrep  { const float* src; unsigned short* dst; int R; int C; int ntile; };
struct WPrepAll { WPrep w[5]; };
__global__ __launch_bounds__(256) void k_prep_w(WPrepAll a){
  __shared__ float tile[64][65];
  int b = blockIdx.x, i = 0;
  while (b >= a.w[i].ntile){ b -= a.w[i].ntile; ++i; }
  const float* src = a.w[i].src; unsigned short* dst = a.w[i].dst;
  int R = a.w[i].R, C = a.w[i].C;
  int tpr = C >> 6;
  int c0 = (b % tpr)*64, r0 = (b / tpr)*64;
  #pragma unroll
  for (int j=0;j<16;++j){
    int idx = j*256 + threadIdx.x; int r = idx>>6, c = idx&63;
    tile[r][c] = src[(size_t)(r0+r)*C + c0 + c];
  }
  __syncthreads();
  #pragma unroll
  for (int j=0;j<16;++j){
    int idx = j*256 + threadIdx.x; int r = idx>>6, c = idx&63;
    dst[(size_t)(c0+r)*R + r0 + c] = f2bf(tile[c][r]);
  }
}

// ---------------- bf16 (R,C) -> bf16 (C,R) transpose ------------------------
__global__ __launch_bounds__(256) void k_transpose_b2b(const unsigned short* __restrict__ src,
    unsigned short* __restrict__ dst, int R, int C){
  __shared__ unsigned short tile[64][72];
  int c0 = blockIdx.x*64, r0 = blockIdx.y*64;
  #pragma unroll
  for (int i=0;i<16;++i){
    int idx = i*256 + threadIdx.x; int r = idx>>6, c = idx&63;
    tile[r][c] = src[(size_t)(r0+r)*C + c0 + c];
  }
  __syncthreads();
  #pragma unroll
  for (int i=0;i<16;++i){
    int idx = i*256 + threadIdx.x; int r = idx>>6, c = idx&63;
    dst[(size_t)(c0+r)*R + r0 + c] = tile[c][r];
  }
}

// ---------------- bf16 GEMM: C(M,N) = A(M,K) * BT(N,K)^T --------------------
template<int MODE>
__global__ __launch_bounds__(256) void k_gemm_bt(
    const unsigned short* __restrict__ A, const unsigned short* __restrict__ BT,
    int M, int N, int K,
    float* __restrict__ out_f32, unsigned short* __restrict__ out_v,
    unsigned short* __restrict__ out_g)
{
  __shared__ __align__(16) short As[128*64];
  __shared__ __align__(16) short Bs[128*64];
  int bn = blockIdx.x*128, bm = blockIdx.y*128;
  int tid = threadIdx.x;
  int w = tid>>6, l = tid&63;
  int wr = w>>1, wc = w&1;
  int lrow = l&31, lhi = l>>5;
  floatx16 acc[2][2];
  #pragma unroll
  for (int a=0;a<2;++a)
    #pragma unroll
    for (int b=0;b<2;++b)
      #pragma unroll
      for (int j=0;j<16;++j) acc[a][b][j]=0.f;

  int kchunk = K / gridDim.z;
  int k_beg = blockIdx.z * kchunk;
  for (int k0=k_beg; k0<k_beg+kchunk; k0+=64){
    __syncthreads();
    #pragma unroll
    for (int i=0;i<4;++i){
      int idx = i*256 + tid; int r = idx>>3, c = idx&7;
      int cs = c ^ (r&7);
      async_cp16((const char*)A  + ((size_t)(bm+r)*K + k0 + cs*8)*2, &As[idx*8]);
      async_cp16((const char*)BT + ((size_t)(bn+r)*K + k0 + cs*8)*2, &Bs[idx*8]);
    }
    __syncthreads();
    #pragma unroll
    for (int kc=0;kc<4;++kc){
      short8 af[2], bf[2];
      #pragma unroll
      for (int tm=0;tm<2;++tm){
        int row = wr*64 + tm*32 + lrow;
        int pos = (2*kc + lhi) ^ (row&7);
        af[tm] = *(const short8*)&As[row*64 + pos*8];
      }
      #pragma unroll
      for (int tn=0;tn<2;++tn){
        int row = wc*64 + tn*32 + lrow;
        int pos = (2*kc + lhi) ^ (row&7);
        bf[tn] = *(const short8*)&Bs[row*64 + pos*8];
      }
      #pragma unroll
      for (int tm=0;tm<2;++tm)
        #pragma unroll
        for (int tn=0;tn<2;++tn)
          acc[tm][tn] = __builtin_amdgcn_mfma_f32_32x32x16_bf16(af[tm], bf[tn], acc[tm][tn], 0,0,0);
    }
  }
  #pragma unroll
  for (int tm=0;tm<2;++tm)
    #pragma unroll
    for (int tn=0;tn<2;++tn)
      #pragma unroll
      for (int r=0;r<16;++r){
        int row = bm + wr*64 + tm*32 + (r&3) + 8*(r>>2) + 4*lhi;
        int col = bn + wc*64 + tn*32 + lrow;
        float v = acc[tm][tn][r];
        if (MODE==0){
          if (col < 2048)      out_f32[(size_t)row*2048 + col] = v;
          else if (col < 4096) out_v[(size_t)row*2048 + (col-2048)] = f2bf(v);
          else                 out_g[(size_t)row*2048 + (col-4096)] = f2bf(v);
        } else {
          atomicAdd(&out_f32[(size_t)row*N + col], v);
        }
      }
}

// ---------------- rotary (theta shift) + k scaling, fp32 -> bf16 ------------
__global__ void k_rotary(const float* __restrict__ qk, const float* __restrict__ sinp,
                         const float* __restrict__ cosp,
                         unsigned short* __restrict__ qrp, unsigned short* __restrict__ krp)
{
  int tid = blockIdx.x*blockDim.x + threadIdx.x;   // T*1024 pair-units
  int t = tid >> 10, p = tid & 1023;
  bool isq = p < 512;
  int c = (isq ? p : p - 512)*2;
  int d = c & 127;
  const float* base = qk + (size_t)t*2048 + (isq ? 0 : 1024) + c;
  float f0 = base[0], f1 = base[1];
  float s0 = sinp[t*128 + d],   s1 = sinp[t*128 + d + 1];
  float c0 = cosp[t*128 + d],   c1 = cosp[t*128 + d + 1];
  float r0 = f0*c0 - f1*s0;
  float r1 = f1*c1 + f0*s1;
  if (!isq){ r0 *= 0.08838834764831845f; r1 *= 0.08838834764831845f; }  // KD^-0.5
  unsigned short* dst = (isq ? qrp : krp) + (size_t)t*1024 + c;
  dst[0] = f2bf(r0); dst[1] = f2bf(r1);
}

// ---------------- retention attention (LDS-free, swapped-QK, pipelined) -----
// 1024 blocks: gid&7 = head, gid>>3 = [qt desc]x[chunk]. 4 waves/block =
// (qhalf x hdhalf); wave = 32 q-rows x 128 hd. Every block's s-range split
// in half across the two chunk blocks; bf16 partial O to chunk-private
// buffers, fp32 partial den to chunk-private slots; k_rmsgate combines.
// QK^T computed SWAPPED: s_ = mfma(K, Q) -> C[s][q] (lane&31 = q-row).
// Decay/mask/den applied in that layout (den = per-lane scalar), then P is
// converted to the PV A-fragment in-register: 8x v_cvt_pk_bf16_f32 +
// 4x v_permlane32_swap_b32 (vdst_hi <-> vsrc_lo). No LDS, no barriers.
__global__ __launch_bounds__(256, 2) void k_attn(
    const unsigned short* __restrict__ qr, const unsigned short* __restrict__ kr,
    const unsigned short* __restrict__ vT,
    unsigned short* __restrict__ o_acc0, unsigned short* __restrict__ o_acc1,
    float* __restrict__ den_g)
{
  int gid = blockIdx.x;
  int head = gid & 7;
  int rest = gid >> 3;                           // 0..127
  int qt = 63 - (rest >> 1);                     // longest blocks first
  int chunk = rest & 1;
  int tid = threadIdx.x;
  int w = tid>>6, l = tid&63;
  int qh = w>>1, hh = w&1;
  int lrow = l&31, lhi = l>>5;
  int tbase = qt*64 + qh*32;                     // wave's first q-row

  float gamma = 1.f - exp2f(-5.f - (float)head);
  float L = log2f(gamma);                        // negative

  int dmax = (int)(40.0f/(-L));                  // decay < 2^-40 beyond: skip
  int s_start = tbase - dmax; if (s_start < 0) s_start = 0; s_start &= ~31;
  int N = ((tbase - s_start) >> 5) + 1;          // number of 32-col s-tiles
  int half = (N+1)>>1;                           // chunk0 = [0,half), chunk1 = [half,N)
  int t0 = chunk ? half : 0;
  int t1 = chunk ? N    : half;

  floatx16 o[4];
  #pragma unroll
  for (int i=0;i<4;++i)
    #pragma unroll
    for (int j=0;j<16;++j) o[i][j]=0.f;
  float den_ = 0.f;

  if (t0 < t1){
    int sb = s_start + t0*32;
    int se = s_start + (t1-1)*32;                // last tile start

    short8 qf[8];                                // B-operand: lane&31 = q-col
    const unsigned short* qbase = qr + (size_t)(tbase+lrow)*1024 + head*128 + lhi*8;
    #pragma unroll
    for (int kc=0;kc<8;++kc) qf[kc] = *(const short8*)(qbase + kc*16);

    // decay factor tables: decay = 2^(L*(qglob - sglob)), qglob=tbase+lrow,
    // sglob=s0+srow(r), srow=(r&3)+8*(r>>2)+4*lhi.
    float lanefac = exp2f(L*((float)lrow - 4.0f*(float)lhi));
    float e1[4], e2[4];
    #pragma unroll
    for (int i=0;i<4;++i){ e1[i] = exp2f(-L*(float)i); e2[i] = exp2f(-L*8.0f*(float)i); }

    const unsigned short* kb = kr + head*128 + lhi*8;
    const unsigned short* vb = vT + (size_t)(head*256 + hh*128)*4096 + lhi*8;

#define LOADK(S0, KF) do{ \
    const unsigned short* kp_ = kb + (size_t)((S0)+lrow)*1024; \
    _Pragma("unroll") \
    for (int kc=0;kc<8;++kc) KF[kc] = *(const short8*)(kp_ + kc*16); \
  }while(0)

#define LOADV(S0, VF) do{ \
    const unsigned short* vp_ = vb + (S0); \
    _Pragma("unroll") \
    for (int nt=0;nt<4;++nt){ \
      const unsigned short* vr_ = vp_ + (size_t)(nt*32+lrow)*4096; \
      _Pragma("unroll") \
      for (int kc=0;kc<2;++kc) VF[nt*2+kc] = *(const short8*)(vr_ + kc*16); \
    } \
  }while(0)

#define COMPUTE(S0, KF, VF) do{ \
    floatx16 s_; \
    _Pragma("unroll") for (int j=0;j<16;++j) s_[j]=0.f; \
    __builtin_amdgcn_s_setprio(1); \
    _Pragma("unroll") \
    for (int kc=0;kc<8;++kc) \
      s_ = __builtin_amdgcn_mfma_f32_32x32x16_bf16(KF[kc], qf[kc], s_, 0,0,0); \
    __builtin_amdgcn_s_setprio(0); \
    float tf_ = exp2f(L*(float)(tbase - (S0))) * lanefac; \
    bool diag_ = ((S0) == tbase); \
    float pv_[16]; \
    _Pragma("unroll") \
    for (int r=0;r<16;++r){ \
      float val_ = s_[r]*(tf_*e1[r&3]*e2[r>>2]); \
      if (diag_){ if (lrow < (r&3)+8*(r>>2)+4*lhi) val_ = 0.f; } \
      den_ += fabsf(val_); \
      pv_[r] = val_; \
    } \
    unsigned int w0_,w1_,w2_,w3_,w4_,w5_,w6_,w7_; \
    asm("v_cvt_pk_bf16_f32 %0, %1, %2" : "=v"(w0_) : "v"(pv_[0]),  "v"(pv_[1])); \
    asm("v_cvt_pk_bf16_f32 %0, %1, %2" : "=v"(w1_) : "v"(pv_[2]),  "v"(pv_[3])); \
    asm("v_cvt_pk_bf16_f32 %0, %1, %2" : "=v"(w2_) : "v"(pv_[4]),  "v"(pv_[5])); \
    asm("v_cvt_pk_bf16_f32 %0, %1, %2" : "=v"(w3_) : "v"(pv_[6]),  "v"(pv_[7])); \
    asm("v_cvt_pk_bf16_f32 %0, %1, %2" : "=v"(w4_) : "v"(pv_[8]),  "v"(pv_[9])); \
    asm("v_cvt_pk_bf16_f32 %0, %1, %2" : "=v"(w5_) : "v"(pv_[10]), "v"(pv_[11])); \
    asm("v_cvt_pk_bf16_f32 %0, %1, %2" : "=v"(w6_) : "v"(pv_[12]), "v"(pv_[13])); \
    asm("v_cvt_pk_bf16_f32 %0, %1, %2" : "=v"(w7_) : "v"(pv_[14]), "v"(pv_[15])); \
    asm("v_permlane32_swap_b32 %0, %1" : "+v"(w0_), "+v"(w2_)); \
    asm("v_permlane32_swap_b32 %0, %1" : "+v"(w1_), "+v"(w3_)); \
    asm("v_permlane32_swap_b32 %0, %1" : "+v"(w4_), "+v"(w6_)); \
    asm("v_permlane32_swap_b32 %0, %1" : "+v"(w5_), "+v"(w7_)); \
    union { unsigned int u[4]; short8 s; } pa0_, pa1_; \
    pa0_.u[0]=w0_; pa0_.u[1]=w1_; pa0_.u[2]=w2_; pa0_.u[3]=w3_; \
    pa1_.u[0]=w4_; pa1_.u[1]=w5_; pa1_.u[2]=w6_; pa1_.u[3]=w7_; \
    __builtin_amdgcn_s_setprio(1); \
    _Pragma("unroll") \
    for (int nt=0;nt<4;++nt){ \
      o[nt] = __builtin_amdgcn_mfma_f32_32x32x16_bf16(pa0_.s, VF[nt*2+0], o[nt], 0,0,0); \
      o[nt] = __builtin_amdgcn_mfma_f32_32x32x16_bf16(pa1_.s, VF[nt*2+1], o[nt], 0,0,0); \
    } \
    __builtin_amdgcn_s_setprio(0); \
  }while(0)

    short8 kfA[8], kfB[8];
    LOADK(sb, kfA);
    for (int s0 = sb;; s0 += 64){
      {
        short8 vfA[8];
        LOADV(s0, vfA);                          // V latency hides under QK chain
        if (s0 + 32 <= se) LOADK(s0+32, kfB);    // K one tile ahead
        COMPUTE(s0, kfA, vfA);
      }
      if (s0 + 32 > se) break;
      {
        short8 vfB[8];
        LOADV(s0+32, vfB);
        if (s0 + 64 <= se) LOADK(s0+64, kfA);
        COMPUTE(s0+32, kfB, vfB);
      }
      if (s0 + 64 > se) break;
    }
#undef LOADK
#undef LOADV
#undef COMPUTE
  }

  // partial den: per-lane scalar; q-row l&31 total = own + partner half.
  // hh waves compute identical den; only hh==0 stores. Unique writer per
  // (chunk,row,head) -> no atomics.
  if (hh == 0){
    float d = den_ + __shfl_xor(den_, 32, 64);
    if (lhi == 0)
      den_g[((size_t)chunk*4096 + tbase + lrow)*8 + head] = d;
  }

  // partial O: bf16 store to the chunk-private buffer (zeros if empty chunk).
  unsigned short* ob = chunk ? o_acc1 : o_acc0;
  #pragma unroll
  for (int nt=0;nt<4;++nt)
    #pragma unroll
    for (int r=0;r<16;++r){
      int row = (r&3)+8*(r>>2)+4*lhi;
      ob[(size_t)(tbase+row)*2048 + head*256 + hh*128 + nt*32 + lrow] = f2bf(o[nt][r]);
    }
}

// ---------------- partial-sum + den-normalize + group RMS + SiLU gate -------
__global__ __launch_bounds__(256) void k_rmsgate(const unsigned short* __restrict__ o_acc0,
    const unsigned short* __restrict__ o_acc1, const unsigned short* __restrict__ g_bf,
    const float* __restrict__ den_g, unsigned short* __restrict__ gated)
{
  int t = blockIdx.x;
  int tid = threadIdx.x;
  int head = tid >> 5;                       // 32 threads = one head group (256)
  float den = den_g[(size_t)t*8 + head] + den_g[(size_t)(4096 + t)*8 + head];
  float rs  = 1.0f/fminf(fmaxf(den, 1.0f), 50000.0f);
  size_t base = (size_t)t*2048 + tid*8;
  short8 av = *(const short8*)(o_acc0 + base);
  short8 bv = *(const short8*)(o_acc1 + base);
  short8 gv = *(const short8*)(g_bf + base);
  float of[8]; float ss = 0.f;
  #pragma unroll
  for (int j=0;j<8;++j){
    of[j] = (bf2f((unsigned short)av[j]) + bf2f((unsigned short)bv[j])) * rs;
    ss += of[j]*of[j];
  }
  #pragma unroll
  for (int off=1; off<32; off<<=1) ss += __shfl_xor(ss, off, 64);
  float rms = rsqrtf(ss*(1.0f/256.0f) + 1e-6f);
  short8 outv;
  #pragma unroll
  for (int j=0;j<8;++j){
    float g = bf2f((unsigned short)gv[j]);
    float si = g / (1.0f + expf(-g));
    outv[j] = (short)f2bf(si * of[j] * rms);
  }
  *(short8*)(gated + base) = outv;
}

// ---------------------------------------------------------------------------
extern "C" void kernel_launch(void* const* d_in, const int* in_sizes, int n_in,
                              void* d_out, int out_size, void* d_ws, size_t ws_size,
                              hipStream_t stream)
{
  const float* x    = (const float*)d_in[0];
  const float* sinp = (const float*)d_in[1];
  const float* cosp = (const float*)d_in[2];
  // d_in[3] = inner_mask: intentionally unused (computed analytically)
  const float* Wq = (const float*)d_in[4];
  const float* Wk = (const float*)d_in[5];
  const float* Wv = (const float*)d_in[6];
  const float* Wg = (const float*)d_in[7];
  const float* Wo = (const float*)d_in[8];

  char* ws = (char*)d_ws;
  size_t off = 0;
  auto alloc = [&](size_t bytes)->char*{ char* p = ws + off; off += (bytes + 255) & ~(size_t)255; return p; };
  unsigned short* x_bf   = (unsigned short*)alloc((size_t)4096*1024*2);  // reused as qr, then gated
  unsigned short* WallT  = (unsigned short*)alloc((size_t)6144*1024*2);  // reused as kr, then gated tail
  float*          qk_f32 = (float*)         alloc((size_t)4096*2048*4);  // reused as o_acc0 (bf16)
  unsigned short* v_bf   = (unsigned short*)alloc((size_t)4096*2048*2);
  unsigned short* g_bf   = (unsigned short*)alloc((size_t)4096*2048*2);
  unsigned short* vT     = (unsigned short*)alloc((size_t)2048*4096*2);
  unsigned short* WoT    = (unsigned short*)alloc((size_t)1024*2048*2);
  unsigned short* o_acc1 = (unsigned short*)alloc((size_t)4096*2048*2);
  float*          den_g  = (float*)         alloc((size_t)2*4096*8*4);
  unsigned short* qrp    = x_bf;                       // alias (x_bf dead after qkvg GEMM)
  unsigned short* krp    = WallT;                      // alias (WallT dead after qkvg GEMM)
  unsigned short* o_acc0 = (unsigned short*)qk_f32;    // alias (qk_f32 dead after rotary)
  unsigned short* gated  = x_bf;                       // alias (qr/kr dead after k_attn; spans x_bf+WallT)

  // d_out is poisoned 0xAA; final GEMM uses atomic split-K -> zero it early
  hipMemsetAsync(d_out, 0, (size_t)4096*1024*4, stream);

  // prep
  k_cvt_x<<<4096, 256, 0, stream>>>(x, x_bf, 4096*1024/4);
  WPrepAll pa;
  pa.w[0] = { Wq, WallT,                        1024, 1024, 256 };
  pa.w[1] = { Wk, WallT + 1024*1024,            1024, 1024, 256 };
  pa.w[2] = { Wv, WallT + 2048*1024,            1024, 2048, 512 };
  pa.w[3] = { Wg, WallT + (size_t)4096*1024,    1024, 2048, 512 };
  pa.w[4] = { Wo, WoT,                          2048, 1024, 512 };
  k_prep_w<<<2048, 256, 0, stream>>>(pa);

  // qkvg = x @ [Wq|Wk|Wv|Wg]
  k_gemm_bt<0><<<dim3(48,32,1), 256, 0, stream>>>(x_bf, WallT, 4096, 6144, 1024, qk_f32, v_bf, g_bf);

  // rotary + k-scaling -> bf16 (overwrites x_bf/WallT aliases)
  k_rotary<<<16384, 256, 0, stream>>>(qk_f32, sinp, cosp, qrp, krp);

  // V^T per head: (t, 2048) -> (2048, t)
  k_transpose_b2b<<<dim3(32,64), 256, 0, stream>>>(v_bf, vT, 4096, 2048);

  // retention attention -> chunk-private bf16 partial O + fp32 partial den
  k_attn<<<1024, 256, 0, stream>>>(qrp, krp, vT, o_acc0, o_acc1, den_g);

  // partial-sum + den-clip divide + RMS(group=256) + silu(g) gate -> gated
  k_rmsgate<<<4096, 256, 0, stream>>>(o_acc0, o_acc1, g_bf, den_g, gated);

  // out = gated @ Wo -> fp32 d_out (split-K=2, atomic accumulate)
  k_gemm_bt<1><<<dim3(8,32,2), 256, 0, stream>>>(gated, WoT, 4096, 1024, 2048,
                                                 (float*)d_out, nullptr, nullptr);

  (void)in_sizes; (void)n_in; (void)out_size; (void)ws_size;
}

// Round 4
// 988.994 us; speedup vs baseline: 1.1615x; 1.0013x over previous
//
#include <hip/hip_runtime.h>

// ---------------------------------------------------------------------------
// MultiScaleRetention forward, MI355X/gfx950.  B=1,T=4096,E=1024,VD=2048,H=8.
// R6: k_attn — 4-way s-chunk split (max 32 tiles/wave, was 64) + prefetch
// pinned with sched_barrier(0) so the compiler can't sink next-tile K loads
// back to their use (R4 failure mode). V issued before K-next so PV's waitcnt
// leaves the K prefetch in flight. Out-GEMM: fp32 atomics (8.4M RMW, R3's
// fabric-amplification pattern) replaced by split-K partial stores + add
// kernel; d_out memset dropped.
// ---------------------------------------------------------------------------

typedef __attribute__((ext_vector_type(8)))  short  short8;
typedef __attribute__((ext_vector_type(16))) float  floatx16;

__device__ inline unsigned short f2bf(float f){
  unsigned int u = __builtin_bit_cast(unsigned int, f);
  unsigned int r = (u + 0x7fffu + ((u >> 16) & 1u)) >> 16;   // RNE
  return (unsigned short)r;
}
__device__ inline float bf2f(unsigned short u){
  unsigned int x = ((unsigned int)u) << 16;
  return __builtin_bit_cast(float, x);
}
__device__ inline void async_cp16(const void* g, const void* l){
  __builtin_amdgcn_global_load_lds((const __attribute__((address_space(1))) void*)g,
                                   (__attribute__((address_space(3))) void*)l, 16, 0, 0);
}

// ---------------- x -> bf16 -------------------------------------------------
struct us4 { unsigned short a,b,c,d; };
__global__ void k_cvt_x(const float* __restrict__ x, unsigned short* __restrict__ xb, int n4){
  int i = blockIdx.x*blockDim.x + threadIdx.x;
  if (i >= n4) return;
  float4 v = ((const float4*)x)[i];
  us4 o = { f2bf(v.x), f2bf(v.y), f2bf(v.z), f2bf(v.w) };
  ((us4*)xb)[i] = o;
}

// ---------------- fused weight transposes (fp32 RxC -> bf16 CxR) ------------
struct WPrep  { const float* src; unsigned short* dst; int R; int C; int ntile; };
struct WPrepAll { WPrep w[5]; };
__global__ __launch_bounds__(256) void k_prep_w(WPrepAll a){
  __shared__ float tile[64][65];
  int b = blockIdx.x, i = 0;
  while (b >= a.w[i].ntile){ b -= a.w[i].ntile; ++i; }
  const float* src = a.w[i].src; unsigned short* dst = a.w[i].dst;
  int R = a.w[i].R, C = a.w[i].C;
  int tpr = C >> 6;
  int c0 = (b % tpr)*64, r0 = (b / tpr)*64;
  #pragma unroll
  for (int j=0;j<16;++j){
    int idx = j*256 + threadIdx.x; int r = idx>>6, c = idx&63;
    tile[r][c] = src[(size_t)(r0+r)*C + c0 + c];
  }
  __syncthreads();
  #pragma unroll
  for (int j=0;j<16;++j){
    int idx = j*256 + threadIdx.x; int r = idx>>6, c = idx&63;
    dst[(size_t)(c0+r)*R + r0 + c] = f2bf(tile[c][r]);
  }
}

// ---------------- bf16 (R,C) -> bf16 (C,R) transpose ------------------------
__global__ __launch_bounds__(256) void k_transpose_b2b(const unsigned short* __restrict__ src,
    unsigned short* __restrict__ dst, int R, int C){
  __shared__ unsigned short tile[64][72];
  int c0 = blockIdx.x*64, r0 = blockIdx.y*64;
  #pragma unroll
  for (int i=0;i<16;++i){
    int idx = i*256 + threadIdx.x; int r = idx>>6, c = idx&63;
    tile[r][c] = src[(size_t)(r0+r)*C + c0 + c];
  }
  __syncthreads();
  #pragma unroll
  for (int i=0;i<16;++i){
    int idx = i*256 + threadIdx.x; int r = idx>>6, c = idx&63;
    dst[(size_t)(c0+r)*R + r0 + c] = tile[c][r];
  }
}

// ---------------- bf16 GEMM: C(M,N) = A(M,K) * BT(N,K)^T --------------------
// MODE 0: qkvg fanout epilogue. MODE 1: plain fp32 store to the blockIdx.z
// partial buffer (split-K without atomics; partials summed by k_addout).
template<int MODE>
__global__ __launch_bounds__(256) void k_gemm_bt(
    const unsigned short* __restrict__ A, const unsigned short* __restrict__ BT,
    int M, int N, int K,
    float* __restrict__ out_f32, unsigned short* __restrict__ out_v,
    unsigned short* __restrict__ out_g)
{
  __shared__ __align__(16) short As[128*64];
  __shared__ __align__(16) short Bs[128*64];
  int bn = blockIdx.x*128, bm = blockIdx.y*128;
  int tid = threadIdx.x;
  int w = tid>>6, l = tid&63;
  int wr = w>>1, wc = w&1;
  int lrow = l&31, lhi = l>>5;
  floatx16 acc[2][2];
  #pragma unroll
  for (int a=0;a<2;++a)
    #pragma unroll
    for (int b=0;b<2;++b)
      #pragma unroll
      for (int j=0;j<16;++j) acc[a][b][j]=0.f;

  int kchunk = K / gridDim.z;
  int k_beg = blockIdx.z * kchunk;
  for (int k0=k_beg; k0<k_beg+kchunk; k0+=64){
    __syncthreads();
    #pragma unroll
    for (int i=0;i<4;++i){
      int idx = i*256 + tid; int r = idx>>3, c = idx&7;
      int cs = c ^ (r&7);
      async_cp16((const char*)A  + ((size_t)(bm+r)*K + k0 + cs*8)*2, &As[idx*8]);
      async_cp16((const char*)BT + ((size_t)(bn+r)*K + k0 + cs*8)*2, &Bs[idx*8]);
    }
    __syncthreads();
    #pragma unroll
    for (int kc=0;kc<4;++kc){
      short8 af[2], bf[2];
      #pragma unroll
      for (int tm=0;tm<2;++tm){
        int row = wr*64 + tm*32 + lrow;
        int pos = (2*kc + lhi) ^ (row&7);
        af[tm] = *(const short8*)&As[row*64 + pos*8];
      }
      #pragma unroll
      for (int tn=0;tn<2;++tn){
        int row = wc*64 + tn*32 + lrow;
        int pos = (2*kc + lhi) ^ (row&7);
        bf[tn] = *(const short8*)&Bs[row*64 + pos*8];
      }
      #pragma unroll
      for (int tm=0;tm<2;++tm)
        #pragma unroll
        for (int tn=0;tn<2;++tn)
          acc[tm][tn] = __builtin_amdgcn_mfma_f32_32x32x16_bf16(af[tm], bf[tn], acc[tm][tn], 0,0,0);
    }
  }
  #pragma unroll
  for (int tm=0;tm<2;++tm)
    #pragma unroll
    for (int tn=0;tn<2;++tn)
      #pragma unroll
      for (int r=0;r<16;++r){
        int row = bm + wr*64 + tm*32 + (r&3) + 8*(r>>2) + 4*lhi;
        int col = bn + wc*64 + tn*32 + lrow;
        float v = acc[tm][tn][r];
        if (MODE==0){
          if (col < 2048)      out_f32[(size_t)row*2048 + col] = v;
          else if (col < 4096) out_v[(size_t)row*2048 + (col-2048)] = f2bf(v);
          else                 out_g[(size_t)row*2048 + (col-4096)] = f2bf(v);
        } else {
          float* dst = out_f32 + (size_t)blockIdx.z*((size_t)M*N);
          dst[(size_t)row*N + col] = v;
        }
      }
}

// ---------------- split-K partial sum -> d_out ------------------------------
__global__ void k_addout(const float* __restrict__ p0, const float* __restrict__ p1,
                         float* __restrict__ out, int n4){
  int i = blockIdx.x*blockDim.x + threadIdx.x;
  if (i >= n4) return;
  float4 a = ((const float4*)p0)[i];
  float4 b = ((const float4*)p1)[i];
  float4 o = {a.x+b.x, a.y+b.y, a.z+b.z, a.w+b.w};
  ((float4*)out)[i] = o;
}

// ---------------- rotary (theta shift) + k scaling, fp32 -> bf16 ------------
__global__ void k_rotary(const float* __restrict__ qk, const float* __restrict__ sinp,
                         const float* __restrict__ cosp,
                         unsigned short* __restrict__ qrp, unsigned short* __restrict__ krp)
{
  int tid = blockIdx.x*blockDim.x + threadIdx.x;   // T*1024 pair-units
  int t = tid >> 10, p = tid & 1023;
  bool isq = p < 512;
  int c = (isq ? p : p - 512)*2;
  int d = c & 127;
  const float* base = qk + (size_t)t*2048 + (isq ? 0 : 1024) + c;
  float f0 = base[0], f1 = base[1];
  float s0 = sinp[t*128 + d],   s1 = sinp[t*128 + d + 1];
  float c0 = cosp[t*128 + d],   c1 = cosp[t*128 + d + 1];
  float r0 = f0*c0 - f1*s0;
  float r1 = f1*c1 + f0*s1;
  if (!isq){ r0 *= 0.08838834764831845f; r1 *= 0.08838834764831845f; }  // KD^-0.5
  unsigned short* dst = (isq ? qrp : krp) + (size_t)t*1024 + c;
  dst[0] = f2bf(r0); dst[1] = f2bf(r1);
}

// ---------------- retention attention (LDS-free, swapped-QK, pipelined) -----
// 2048 blocks: gid&7 = head (head<->XCD affinity), gid>>3 = [qt desc]x[chunk4].
// 4 waves/block = (qhalf x hdhalf); wave = 32 q-rows x 128 hd. Every block's
// s-range split into 4 chunks (max 32 tiles/wave); bf16 partial O to
// chunk-private quarter of o_parts, fp32 partial den to chunk-private slots;
// k_rmsgate combines all 4. QK^T computed SWAPPED: mfma(K,Q) -> C[s][q]
// (lane&31 = q-row); decay/mask/den in that layout (den per-lane scalar);
// P -> PV A-fragment in-register (8x v_cvt_pk_bf16_f32 + 4x permlane32_swap).
// Prefetch discipline per tile: LOADV(cur); LOADK(next); sched_barrier(0);
// COMPUTE(cur). V older than K-next in vmcnt order, so waiting on V for PV
// leaves the K prefetch in flight; sched_barrier stops the compiler from
// sinking the loads to their use (R4 failure). No LDS, no barriers.
__global__ __launch_bounds__(256, 2) void k_attn(
    const unsigned short* __restrict__ qr, const unsigned short* __restrict__ kr,
    const unsigned short* __restrict__ vT,
    unsigned short* __restrict__ o_parts, float* __restrict__ den_g)
{
  int gid = blockIdx.x;
  int head = gid & 7;
  int rest = gid >> 3;                           // 0..255
  int qt = 63 - (rest >> 2);                     // longest blocks first
  int chunk = rest & 3;
  int tid = threadIdx.x;
  int w = tid>>6, l = tid&63;
  int qh = w>>1, hh = w&1;
  int lrow = l&31, lhi = l>>5;
  int tbase = qt*64 + qh*32;                     // wave's first q-row

  float gamma = 1.f - exp2f(-5.f - (float)head);
  float L = log2f(gamma);                        // negative

  int dmax = (int)(40.0f/(-L));                  // decay < 2^-40 beyond: skip
  int s_start = tbase - dmax; if (s_start < 0) s_start = 0; s_start &= ~31;
  int N = ((tbase - s_start) >> 5) + 1;          // number of 32-col s-tiles
  int q4 = (N+3)>>2;                             // tiles per chunk (ceil)
  int t0 = chunk*q4;
  int t1 = t0 + q4; if (t1 > N) t1 = N;

  floatx16 o[4];
  #pragma unroll
  for (int i=0;i<4;++i)
    #pragma unroll
    for (int j=0;j<16;++j) o[i][j]=0.f;
  float den_ = 0.f;

  if (t0 < t1){
    int sb = s_start + t0*32;
    int se = s_start + (t1-1)*32;                // last tile start

    short8 qf[8];                                // B-operand: lane&31 = q-col
    const unsigned short* qbase = qr + (size_t)(tbase+lrow)*1024 + head*128 + lhi*8;
    #pragma unroll
    for (int kc=0;kc<8;++kc) qf[kc] = *(const short8*)(qbase + kc*16);

    // decay = 2^(L*(qglob - sglob)), qglob=tbase+lrow, sglob=s0+srow(r),
    // srow=(r&3)+8*(r>>2)+4*lhi.
    float lanefac = exp2f(L*((float)lrow - 4.0f*(float)lhi));
    float e1[4], e2[4];
    #pragma unroll
    for (int i=0;i<4;++i){ e1[i] = exp2f(-L*(float)i); e2[i] = exp2f(-L*8.0f*(float)i); }

    const unsigned short* kb = kr + head*128 + lhi*8;
    const unsigned short* vb = vT + (size_t)(head*256 + hh*128)*4096 + lhi*8;

#define LOADK(S0, KF) do{ \
    const unsigned short* kp_ = kb + (size_t)((S0)+lrow)*1024; \
    _Pragma("unroll") \
    for (int kc=0;kc<8;++kc) KF[kc] = *(const short8*)(kp_ + kc*16); \
  }while(0)

#define LOADV(S0, VF) do{ \
    const unsigned short* vp_ = vb + (S0); \
    _Pragma("unroll") \
    for (int nt=0;nt<4;++nt){ \
      const unsigned short* vr_ = vp_ + (size_t)(nt*32+lrow)*4096; \
      _Pragma("unroll") \
      for (int kc=0;kc<2;++kc) VF[nt*2+kc] = *(const short8*)(vr_ + kc*16); \
    } \
  }while(0)

#define COMPUTE(S0, KF, VF) do{ \
    floatx16 s_; \
    _Pragma("unroll") for (int j=0;j<16;++j) s_[j]=0.f; \
    __builtin_amdgcn_s_setprio(1); \
    _Pragma("unroll") \
    for (int kc=0;kc<8;++kc) \
      s_ = __builtin_amdgcn_mfma_f32_32x32x16_bf16(KF[kc], qf[kc], s_, 0,0,0); \
    __builtin_amdgcn_s_setprio(0); \
    float tf_ = exp2f(L*(float)(tbase - (S0))) * lanefac; \
    bool diag_ = ((S0) == tbase); \
    float pv_[16]; \
    _Pragma("unroll") \
    for (int r=0;r<16;++r){ \
      float val_ = s_[r]*(tf_*e1[r&3]*e2[r>>2]); \
      if (diag_){ if (lrow < (r&3)+8*(r>>2)+4*lhi) val_ = 0.f; } \
      den_ += fabsf(val_); \
      pv_[r] = val_; \
    } \
    unsigned int w0_,w1_,w2_,w3_,w4_,w5_,w6_,w7_; \
    asm("v_cvt_pk_bf16_f32 %0, %1, %2" : "=v"(w0_) : "v"(pv_[0]),  "v"(pv_[1])); \
    asm("v_cvt_pk_bf16_f32 %0, %1, %2" : "=v"(w1_) : "v"(pv_[2]),  "v"(pv_[3])); \
    asm("v_cvt_pk_bf16_f32 %0, %1, %2" : "=v"(w2_) : "v"(pv_[4]),  "v"(pv_[5])); \
    asm("v_cvt_pk_bf16_f32 %0, %1, %2" : "=v"(w3_) : "v"(pv_[6]),  "v"(pv_[7])); \
    asm("v_cvt_pk_bf16_f32 %0, %1, %2" : "=v"(w4_) : "v"(pv_[8]),  "v"(pv_[9])); \
    asm("v_cvt_pk_bf16_f32 %0, %1, %2" : "=v"(w5_) : "v"(pv_[10]), "v"(pv_[11])); \
    asm("v_cvt_pk_bf16_f32 %0, %1, %2" : "=v"(w6_) : "v"(pv_[12]), "v"(pv_[13])); \
    asm("v_cvt_pk_bf16_f32 %0, %1, %2" : "=v"(w7_) : "v"(pv_[14]), "v"(pv_[15])); \
    asm("v_permlane32_swap_b32 %0, %1" : "+v"(w0_), "+v"(w2_)); \
    asm("v_permlane32_swap_b32 %0, %1" : "+v"(w1_), "+v"(w3_)); \
    asm("v_permlane32_swap_b32 %0, %1" : "+v"(w4_), "+v"(w6_)); \
    asm("v_permlane32_swap_b32 %0, %1" : "+v"(w5_), "+v"(w7_)); \
    union { unsigned int u[4]; short8 s; } pa0_, pa1_; \
    pa0_.u[0]=w0_; pa0_.u[1]=w1_; pa0_.u[2]=w2_; pa0_.u[3]=w3_; \
    pa1_.u[0]=w4_; pa1_.u[1]=w5_; pa1_.u[2]=w6_; pa1_.u[3]=w7_; \
    __builtin_amdgcn_s_setprio(1); \
    _Pragma("unroll") \
    for (int nt=0;nt<4;++nt){ \
      o[nt] = __builtin_amdgcn_mfma_f32_32x32x16_bf16(pa0_.s, VF[nt*2+0], o[nt], 0,0,0); \
      o[nt] = __builtin_amdgcn_mfma_f32_32x32x16_bf16(pa1_.s, VF[nt*2+1], o[nt], 0,0,0); \
    } \
    __builtin_amdgcn_s_setprio(0); \
  }while(0)

    short8 kfA[8], kfB[8];
    LOADK(sb, kfA);
    for (int s0 = sb;; s0 += 64){
      {
        short8 vfA[8];
        LOADV(s0, vfA);                          // V first (older in vmcnt order)
        if (s0 + 32 <= se) LOADK(s0+32, kfB);    // K one tile ahead
        __builtin_amdgcn_sched_barrier(0);       // pin: loads issued before MFMAs
        COMPUTE(s0, kfA, vfA);
      }
      if (s0 + 32 > se) break;
      {
        short8 vfB[8];
        LOADV(s0+32, vfB);
        if (s0 + 64 <= se) LOADK(s0+64, kfA);
        __builtin_amdgcn_sched_barrier(0);
        COMPUTE(s0+32, kfB, vfB);
      }
      if (s0 + 64 > se) break;
    }
#undef LOADK
#undef LOADV
#undef COMPUTE
  }

  // partial den: per-lane scalar; q-row l&31 total = own + partner half.
  // hh waves compute identical den; only hh==0 stores. Unique writer per
  // (chunk,row,head) -> no atomics.
  if (hh == 0){
    float d = den_ + __shfl_xor(den_, 32, 64);
    if (lhi == 0)
      den_g[((size_t)chunk*4096 + tbase + lrow)*8 + head] = d;
  }

  // partial O: bf16 store to the chunk-private quarter (zeros if empty chunk).
  unsigned short* ob = o_parts + (size_t)chunk*4096*2048;
  #pragma unroll
  for (int nt=0;nt<4;++nt)
    #pragma unroll
    for (int r=0;r<16;++r){
      int row = (r&3)+8*(r>>2)+4*lhi;
      ob[(size_t)(tbase+row)*2048 + head*256 + hh*128 + nt*32 + lrow] = f2bf(o[nt][r]);
    }
}

// ---------------- partial-sum + den-normalize + group RMS + SiLU gate -------
__global__ __launch_bounds__(256) void k_rmsgate(const unsigned short* __restrict__ o_parts,
    const unsigned short* __restrict__ g_bf, const float* __restrict__ den_g,
    unsigned short* __restrict__ gated)
{
  int t = blockIdx.x;
  int tid = threadIdx.x;
  int head = tid >> 5;                       // 32 threads = one head group (256)
  float den = den_g[(size_t)t*8 + head]
            + den_g[(size_t)( 4096 + t)*8 + head]
            + den_g[(size_t)( 8192 + t)*8 + head]
            + den_g[(size_t)(12288 + t)*8 + head];
  float rs  = 1.0f/fminf(fmaxf(den, 1.0f), 50000.0f);
  size_t base = (size_t)t*2048 + tid*8;
  const size_t CS = (size_t)4096*2048;
  short8 a0 = *(const short8*)(o_parts + base);
  short8 a1 = *(const short8*)(o_parts + CS + base);
  short8 a2 = *(const short8*)(o_parts + 2*CS + base);
  short8 a3 = *(const short8*)(o_parts + 3*CS + base);
  short8 gv = *(const short8*)(g_bf + base);
  float of[8]; float ss = 0.f;
  #pragma unroll
  for (int j=0;j<8;++j){
    of[j] = (bf2f((unsigned short)a0[j]) + bf2f((unsigned short)a1[j])
           + bf2f((unsigned short)a2[j]) + bf2f((unsigned short)a3[j])) * rs;
    ss += of[j]*of[j];
  }
  #pragma unroll
  for (int off=1; off<32; off<<=1) ss += __shfl_xor(ss, off, 64);
  float rms = rsqrtf(ss*(1.0f/256.0f) + 1e-6f);
  short8 outv;
  #pragma unroll
  for (int j=0;j<8;++j){
    float g = bf2f((unsigned short)gv[j]);
    float si = g / (1.0f + expf(-g));
    outv[j] = (short)f2bf(si * of[j] * rms);
  }
  *(short8*)(gated + base) = outv;
}

// ---------------------------------------------------------------------------
extern "C" void kernel_launch(void* const* d_in, const int* in_sizes, int n_in,
                              void* d_out, int out_size, void* d_ws, size_t ws_size,
                              hipStream_t stream)
{
  const float* x    = (const float*)d_in[0];
  const float* sinp = (const float*)d_in[1];
  const float* cosp = (const float*)d_in[2];
  // d_in[3] = inner_mask: intentionally unused (computed analytically)
  const float* Wq = (const float*)d_in[4];
  const float* Wk = (const float*)d_in[5];
  const float* Wv = (const float*)d_in[6];
  const float* Wg = (const float*)d_in[7];
  const float* Wo = (const float*)d_in[8];

  char* ws = (char*)d_ws;
  size_t off = 0;
  auto alloc = [&](size_t bytes)->char*{ char* p = ws + off; off += (bytes + 255) & ~(size_t)255; return p; };
  unsigned short* x_bf   = (unsigned short*)alloc((size_t)4096*1024*2);  // reused as qr, then gated head
  unsigned short* WallT  = (unsigned short*)alloc((size_t)6144*1024*2);  // reused as kr, then gated tail
  float*          qk_f32 = (float*)         alloc((size_t)4096*2048*4);
  unsigned short* v_bf   = (unsigned short*)alloc((size_t)4096*2048*2);
  unsigned short* g_bf   = (unsigned short*)alloc((size_t)4096*2048*2);
  unsigned short* vT     = (unsigned short*)alloc((size_t)2048*4096*2);
  unsigned short* WoT    = (unsigned short*)alloc((size_t)1024*2048*2);
  unsigned short* o_parts= (unsigned short*)alloc((size_t)4*4096*2048*2); // 4 bf16 chunk partials
  float*          den_g  = (float*)         alloc((size_t)4*4096*8*4);
  float*          p_out2 = (float*)         alloc((size_t)2*4096*1024*4); // split-K fp32 partials
  unsigned short* qrp    = x_bf;                       // alias (x_bf dead after qkvg GEMM)
  unsigned short* krp    = WallT;                      // alias (WallT dead after qkvg GEMM)
  unsigned short* gated  = x_bf;                       // alias (qr/kr dead after k_attn; spans x_bf+WallT)

  // prep
  k_cvt_x<<<4096, 256, 0, stream>>>(x, x_bf, 4096*1024/4);
  WPrepAll pa;
  pa.w[0] = { Wq, WallT,                        1024, 1024, 256 };
  pa.w[1] = { Wk, WallT + 1024*1024,            1024, 1024, 256 };
  pa.w[2] = { Wv, WallT + 2048*1024,            1024, 2048, 512 };
  pa.w[3] = { Wg, WallT + (size_t)4096*1024,    1024, 2048, 512 };
  pa.w[4] = { Wo, WoT,                          2048, 1024, 512 };
  k_prep_w<<<2048, 256, 0, stream>>>(pa);

  // qkvg = x @ [Wq|Wk|Wv|Wg]
  k_gemm_bt<0><<<dim3(48,32,1), 256, 0, stream>>>(x_bf, WallT, 4096, 6144, 1024, qk_f32, v_bf, g_bf);

  // rotary + k-scaling -> bf16 (overwrites x_bf/WallT aliases)
  k_rotary<<<16384, 256, 0, stream>>>(qk_f32, sinp, cosp, qrp, krp);

  // V^T per head: (t, 2048) -> (2048, t)
  k_transpose_b2b<<<dim3(32,64), 256, 0, stream>>>(v_bf, vT, 4096, 2048);

  // retention attention -> 4 chunk-private bf16 partial O + fp32 partial den
  k_attn<<<2048, 256, 0, stream>>>(qrp, krp, vT, o_parts, den_g);

  // partial-sum + den-clip divide + RMS(group=256) + silu(g) gate -> gated
  k_rmsgate<<<4096, 256, 0, stream>>>(o_parts, g_bf, den_g, gated);

  // out = gated @ Wo -> split-K=2 fp32 partials (plain stores), then sum
  k_gemm_bt<1><<<dim3(8,32,2), 256, 0, stream>>>(gated, WoT, 4096, 1024, 2048,
                                                 p_out2, nullptr, nullptr);
  k_addout<<<4096, 256, 0, stream>>>(p_out2, p_out2 + (size_t)4096*1024,
                                     (float*)d_out, 4096*1024/4);

  (void)in_sizes; (void)n_in; (void)out_size; (void)ws_size;
}